// Round 5
// baseline (313.222 us; speedup 1.0000x reference)
//
#include <hip/hip_runtime.h>

// ---------------------------------------------------------------------------
// Fused causal attention, MI355X gfx950.
// cast fp32->f16 -> QKV GEMM -> V transpose -> flash attention (strip-paired,
// dbuf gld16 K/V, XOR-swizzled LDS, bpermute P-transform) -> out GEMM.
// MFMA 16x16x32 layouts (m89/m91/m120-verified):
//   A-frag: A[m=lane&15][k=(lane>>4)*8+j], j=0..7
//   B-frag: B[k=(lane>>4)*8+j][n=lane&15]
//   C/D   : row=(lane>>4)*4+reg, col=lane&15
// Attention swap: St = K*Q^T (C: row=key,col=q), O^T = V^T*P.
// LDS tiles are [16-row groups][32 ushorts]; 16B chunk c of row r stored at
// position c ^ swz4(r), swz4(r)=(r&3)^((r>>2)&3) -> b128 frag reads tile all
// 32 banks conflict-free (64B-row layouts otherwise alias 4-way).
// ---------------------------------------------------------------------------

typedef _Float16 f16x8 __attribute__((ext_vector_type(8)));
typedef float floatx4 __attribute__((ext_vector_type(4)));

union U4H8 { uint4 u; f16x8 h; };

__device__ __forceinline__ int swz4(int r) { return (r & 3) ^ ((r >> 2) & 3); }

__device__ __forceinline__ ushort f32_to_h_bits(float f) {
  _Float16 h = (_Float16)f;
  return __builtin_bit_cast(ushort, h);
}
__device__ __forceinline__ uint pack2h(float a, float b) {
  return (uint)f32_to_h_bits(a) | ((uint)f32_to_h_bits(b) << 16);
}

// async global->LDS, 16B/lane; LDS dest = wave-uniform base + lane*16
__device__ __forceinline__ void gld16(const void* g, void* l) {
  __builtin_amdgcn_global_load_lds(
      (const __attribute__((address_space(1))) unsigned char*)g,
      (__attribute__((address_space(3))) unsigned char*)l, 16, 0, 0);
}

// ---------------------------------------------------------------- cast kernel
__global__ __launch_bounds__(256) void cast_f32_f16(const float* __restrict__ in,
                                                    ushort* __restrict__ out) {
  int i = blockIdx.x * 256 + threadIdx.x;
  float4 v = ((const float4*)in)[i];
  ushort4 o;
  o.x = f32_to_h_bits(v.x);
  o.y = f32_to_h_bits(v.y);
  o.z = f32_to_h_bits(v.z);
  o.w = f32_to_h_bits(v.w);
  ((ushort4*)out)[i] = o;
}

// ------------------------------------------------------------------ GEMM B^T
// C[M,N] = A[M,K] * B[N,K]^T.  128x128 tile, BK=32, 4 waves 2x2, 4x4 MFMA.
// XOR-swizzled LDS chunks (see header) kill the m98-style 4-way conflicts.
template <int OUT_F16>
__global__ __launch_bounds__(256) void gemm_bt(const ushort* __restrict__ A,
                                               const ushort* __restrict__ B,
                                               void* __restrict__ Cv,
                                               int M, int N, int K) {
  __shared__ ushort As[128 * 32];
  __shared__ ushort Bs[128 * 32];

  const int tid = threadIdx.x;
  const int lane = tid & 63;
  const int wid = tid >> 6;
  const int l15 = lane & 15;
  const int quad = lane >> 4;
  const int m0 = blockIdx.y * 128;
  const int n0 = blockIdx.x * 128;
  const int wm = (wid & 1) * 64;
  const int wn = (wid >> 1) * 64;

  floatx4 acc[4][4];
#pragma unroll
  for (int i = 0; i < 4; i++)
#pragma unroll
    for (int j = 0; j < 4; j++) acc[i][j] = (floatx4){0.f, 0.f, 0.f, 0.f};

  const int srow = tid >> 2;
  const int scol = (((tid & 3) ^ swz4(srow & 15)) * 8);  // swizzled source chunk
  const ushort* Ap0 = A + (size_t)(m0 + srow) * K + scol;
  const ushort* Ap1 = A + (size_t)(m0 + 64 + srow) * K + scol;
  const ushort* Bp0 = B + (size_t)(n0 + srow) * K + scol;
  const ushort* Bp1 = B + (size_t)(n0 + 64 + srow) * K + scol;
  ushort* AsW = As + wid * 512;
  ushort* BsW = Bs + wid * 512;

  const int rsw = (quad ^ swz4(l15)) * 8;  // swizzled frag-read chunk

  for (int k0 = 0; k0 < K; k0 += 32) {
    __syncthreads();
    gld16(Ap0 + k0, AsW);
    gld16(Ap1 + k0, AsW + 2048);
    gld16(Bp0 + k0, BsW);
    gld16(Bp1 + k0, BsW + 2048);
    __syncthreads();

    U4H8 af[4], bf[4];
#pragma unroll
    for (int mi = 0; mi < 4; mi++)
      af[mi].u = *(const uint4*)&As[(wm + mi * 16 + l15) * 32 + rsw];
#pragma unroll
    for (int ni = 0; ni < 4; ni++)
      bf[ni].u = *(const uint4*)&Bs[(wn + ni * 16 + l15) * 32 + rsw];
#pragma unroll
    for (int mi = 0; mi < 4; mi++)
#pragma unroll
      for (int ni = 0; ni < 4; ni++)
        acc[mi][ni] = __builtin_amdgcn_mfma_f32_16x16x32_f16(af[mi].h, bf[ni].h,
                                                             acc[mi][ni], 0, 0, 0);
  }

#pragma unroll
  for (int mi = 0; mi < 4; mi++) {
#pragma unroll
    for (int r = 0; r < 4; r++) {
      size_t row = m0 + wm + mi * 16 + quad * 4 + r;
#pragma unroll
      for (int ni = 0; ni < 4; ni++) {
        size_t col = n0 + wn + ni * 16 + l15;
        float v = acc[mi][ni][r];
        if (OUT_F16)
          ((ushort*)Cv)[row * N + col] = f32_to_h_bits(v);
        else
          ((float*)Cv)[row * N + col] = v;
      }
    }
  }
}

// --------------------------------------------------------------- V transpose
// qkv [8192][3072] f16 -> vtg[bh=64][dh=64][key=2048] f16.
__global__ __launch_bounds__(256) void vtrans(const ushort* __restrict__ qkv,
                                              ushort* __restrict__ vtg) {
  __shared__ ushort T[64 * 66];
  const int tid = threadIdx.x;
  const int kt = blockIdx.x;
  const int bh = blockIdx.y;
  const int b = bh >> 4, h = bh & 15;

  const int r = tid >> 3;
  const int c = (tid & 7) * 8;
  const ushort* src = qkv + (size_t)(b * 2048 + kt * 64) * 3072 + 2048 + h * 64;
  uint4 v0 = *(const uint4*)(src + (size_t)r * 3072 + c);
  uint4 v1 = *(const uint4*)(src + (size_t)(r + 32) * 3072 + c);
  union { uint4 u; ushort s[8]; } a0, a1;
  a0.u = v0; a1.u = v1;
#pragma unroll
  for (int j = 0; j < 8; j++) {
    T[(c + j) * 66 + r] = a0.s[j];
    T[(c + j) * 66 + r + 32] = a1.s[j];
  }
  __syncthreads();

  const int d = tid >> 3;
  const int kc = (tid & 7) * 8;
  ushort* dst = vtg + (size_t)bh * 64 * 2048 + (size_t)kt * 64;
  union { uint u[4]; uint4 u4; } o0, o1;
#pragma unroll
  for (int i = 0; i < 4; i++) {
    o0.u[i] = *(const uint*)&T[d * 66 + kc + 2 * i];
    o1.u[i] = *(const uint*)&T[(d + 32) * 66 + kc + 2 * i];
  }
  *(uint4*)(dst + (size_t)d * 2048 + kc) = o0.u4;
  *(uint4*)(dst + (size_t)(d + 32) * 2048 + kc) = o1.u4;
}

// ------------------------------------------------------------ flash attention
// Block = strip pair (bx, 31-bx); wave w owns q granules qA=bx*64+w*16,
// qB=(31-bx)*64+w*16 -> uniform 33 strip-tile units/block, 1024 blocks.
// K/V dbuf via gld16 into swizzled [64][32] chunks (conflict-free b128 reads).
// P C-layout -> PV B-frag via ds_bpermute (no LDS round-trip, no lgkm drain):
//   value(key,q) lives in lane q+16*((key>>2)&3), pair reg (key&3)>>1.
__global__ __launch_bounds__(256, 4) void attn_fused(const ushort* __restrict__ qkv,
                                                     const ushort* __restrict__ vtg,
                                                     ushort* __restrict__ attn_out) {
  __shared__ ushort Ks[2][2][64 * 32];  // [buf][kc_dh][row][32]   16 KB
  __shared__ ushort Vs[2][2][64 * 32];  // [buf][kc_key][row][32]  16 KB

  const int tid = threadIdx.x;
  const int lane = tid & 63;
  const int w = tid >> 6;
  const int l15 = lane & 15;
  const int quad = lane >> 4;
  const int bx = blockIdx.x;            // 0..15
  const int bh = blockIdx.y;
  const int b = bh >> 4;
  const int h = bh & 15;
  const int bS = b * 2048;
  const int qtA = bx;
  const int qtB = 31 - bx;
  const int ktmax = qtB;
  int q0s[2];
  q0s[0] = qtA * 64 + w * 16;
  q0s[1] = qtB * 64 + w * 16;

  // bpermute addresses: srclane = l15 + 32*(quad&1) + 16*(i>>1)
  const int bpa0 = (l15 + 32 * (quad & 1)) * 4;
  const int bpa1 = bpa0 + 64;
  const int selhi = quad >> 1;  // th select (dest quads 2,3 take t=...+1)

  // Q B-frags (B[k=dh][n=q] == Q[q][dh]), pre-scaled by 1/sqrt(64)
  U4H8 qf[2][2];
#pragma unroll
  for (int s = 0; s < 2; s++) {
    const ushort* qrow = qkv + (size_t)(bS + q0s[s] + l15) * 3072 + h * 64;
#pragma unroll
    for (int kc = 0; kc < 2; kc++) {
      qf[s][kc].u = *(const uint4*)(qrow + kc * 32 + quad * 8);
      qf[s][kc].h = qf[s][kc].h * (_Float16)0.125f;
    }
  }

  floatx4 o[2][4];  // [strip][dh tile]; D: dh=ni*16+quad*4+r, q=l15
#pragma unroll
  for (int s = 0; s < 2; s++)
#pragma unroll
    for (int ni = 0; ni < 4; ni++) o[s][ni] = (floatx4){0.f, 0.f, 0.f, 0.f};
  float m_i[2] = {-1e30f, -1e30f}, l_i[2] = {0.f, 0.f};

  const ushort* kbase = qkv + (size_t)bS * 3072 + 1024 + h * 64;
  const ushort* vbase = vtg + (size_t)bh * 64 * 2048;
  const int srow = lane >> 2;                             // row in 16-row group
  const int scc = ((lane & 3) ^ swz4(srow)) * 8;          // swizzled src chunk
  const int rsw = (quad ^ swz4(l15)) * 8;                 // swizzled read chunk

  auto stage = [&](int kt, int buf) {
    const ushort* kg = kbase + (size_t)(kt * 64 + w * 16 + srow) * 3072 + scc;
    gld16(kg, &Ks[buf][0][w * 512]);
    gld16(kg + 32, &Ks[buf][1][w * 512]);
    const ushort* vg = vbase + (size_t)(w * 16 + srow) * 2048 + kt * 64 + scc;
    gld16(vg, &Vs[buf][0][w * 512]);
    gld16(vg + 32, &Vs[buf][1][w * 512]);
  };

  auto strip_step = [&](int s, bool diag, int kt64, int buf) {
    // ---- St = K Q^T
    floatx4 s4[4];
#pragma unroll
    for (int t = 0; t < 4; t++) {
      U4H8 kf0, kf1;
      kf0.u = *(const uint4*)&Ks[buf][0][(t * 16 + l15) * 32 + rsw];
      kf1.u = *(const uint4*)&Ks[buf][1][(t * 16 + l15) * 32 + rsw];
      floatx4 sa = (floatx4){0.f, 0.f, 0.f, 0.f};
      sa = __builtin_amdgcn_mfma_f32_16x16x32_f16(kf0.h, qf[s][0].h, sa, 0, 0, 0);
      sa = __builtin_amdgcn_mfma_f32_16x16x32_f16(kf1.h, qf[s][1].h, sa, 0, 0, 0);
      s4[t] = sa;
    }
    if (diag) {
      const int q = q0s[s] + l15;
#pragma unroll
      for (int t = 0; t < 4; t++)
#pragma unroll
        for (int r = 0; r < 4; r++) {
          int key = kt64 + t * 16 + quad * 4 + r;
          if (key > q) s4[t][r] = -1e30f;
        }
    }

    // ---- online softmax (16 in-lane keys + quads via shfl 16/32)
    float tmax = -1e30f;
#pragma unroll
    for (int t = 0; t < 4; t++)
#pragma unroll
      for (int r = 0; r < 4; r++) tmax = fmaxf(tmax, s4[t][r]);
    tmax = fmaxf(tmax, __shfl_xor(tmax, 16));
    tmax = fmaxf(tmax, __shfl_xor(tmax, 32));
    float mnew = fmaxf(m_i[s], tmax);
    float alpha = __expf(m_i[s] - mnew);
    m_i[s] = mnew;
    float rs = 0.f;
#pragma unroll
    for (int t = 0; t < 4; t++)
#pragma unroll
      for (int r = 0; r < 4; r++) {
        float p = __expf(s4[t][r] - mnew);
        s4[t][r] = p;
        rs += p;
      }
    rs += __shfl_xor(rs, 16);
    rs += __shfl_xor(rs, 32);
    l_i[s] = l_i[s] * alpha + rs;
#pragma unroll
    for (int ni = 0; ni < 4; ni++) o[s][ni] *= alpha;

    // ---- pack P pairs: pk[t][pair] = halves (r=2*pair, 2*pair+1)
    uint pk[4][2];
#pragma unroll
    for (int t = 0; t < 4; t++) {
      pk[t][0] = pack2h(s4[t][0], s4[t][1]);
      pk[t][1] = pack2h(s4[t][2], s4[t][3]);
    }

    // ---- O^T += V^T P ; B-frag built by bpermute
#pragma unroll
    for (int kc = 0; kc < 2; kc++) {
      U4H8 pb;
#pragma unroll
      for (int i = 0; i < 4; i++) {
        int addr = (i >> 1) ? bpa1 : bpa0;
        int lo = __builtin_amdgcn_ds_bpermute(addr, (int)pk[kc * 2][i & 1]);
        int hi = __builtin_amdgcn_ds_bpermute(addr, (int)pk[kc * 2 + 1][i & 1]);
        ((uint*)&pb.u)[i] = (uint)(selhi ? hi : lo);
      }
#pragma unroll
      for (int ni = 0; ni < 4; ni++) {
        U4H8 vf;
        vf.u = *(const uint4*)&Vs[buf][kc][(ni * 16 + l15) * 32 + rsw];
        o[s][ni] = __builtin_amdgcn_mfma_f32_16x16x32_f16(vf.h, pb.h, o[s][ni], 0, 0, 0);
      }
    }
  };

  stage(0, 0);
  for (int kt = 0; kt <= ktmax; ++kt) {
    const int buf = kt & 1;
    __syncthreads();  // drains vmcnt -> buf staged; prior LDS reads done
    if (kt < ktmax) stage(kt + 1, buf ^ 1);
    strip_step(1, kt == qtB, kt * 64, buf);
    if (kt <= qtA) strip_step(0, kt == qtA, kt * 64, buf);
  }

  // ---- epilogue: O^T -> q-major rows via the same bpermute transform
#pragma unroll
  for (int s = 0; s < 2; s++) {
    float inv = 1.0f / l_i[s];
    uint pko[4][2];
#pragma unroll
    for (int ni = 0; ni < 4; ni++) {
      pko[ni][0] = pack2h(o[s][ni][0] * inv, o[s][ni][1] * inv);
      pko[ni][1] = pack2h(o[s][ni][2] * inv, o[s][ni][3] * inv);
    }
    ushort* orow = attn_out + (size_t)(bS + q0s[s] + l15) * 1024 + h * 64;
#pragma unroll
    for (int p = 0; p < 2; p++) {
      uint4 x;
#pragma unroll
      for (int i = 0; i < 4; i++) {
        int addr = (i >> 1) ? bpa1 : bpa0;
        int lo = __builtin_amdgcn_ds_bpermute(addr, (int)pko[p * 2][i & 1]);
        int hi = __builtin_amdgcn_ds_bpermute(addr, (int)pko[p * 2 + 1][i & 1]);
        ((uint*)&x)[i] = (uint)(selhi ? hi : lo);
      }
      *(uint4*)(orow + p * 32 + quad * 8) = x;
    }
  }
}

// ---------------------------------------------------------------------- launch
extern "C" void kernel_launch(void* const* d_in, const int* in_sizes, int n_in,
                              void* d_out, int out_size, void* d_ws, size_t ws_size,
                              hipStream_t stream) {
  const float* x = (const float*)d_in[0];       // [4,2048,1024]
  const float* wqkv = (const float*)d_in[1];    // [3072,1024]
  const float* wo = (const float*)d_in[2];      // [1024,1024]
  float* out = (float*)d_out;                   // [4,2048,1024] fp32

  ushort* xh = (ushort*)d_ws;                          // 8192*1024
  ushort* wqkvh = xh + (size_t)8192 * 1024;            // 3072*1024
  ushort* woh = wqkvh + (size_t)3072 * 1024;           // 1024*1024
  ushort* qkvh = woh + (size_t)1024 * 1024;            // 8192*3072
  ushort* attnh = qkvh + (size_t)8192 * 3072;          // 8192*1024
  ushort* vtg = attnh + (size_t)8192 * 1024;           // 64*64*2048
  // total ws use: ~109 MB

  cast_f32_f16<<<8192, 256, 0, stream>>>(x, xh);
  cast_f32_f16<<<3072, 256, 0, stream>>>(wqkv, wqkvh);
  cast_f32_f16<<<1024, 256, 0, stream>>>(wo, woh);

  gemm_bt<1><<<dim3(24, 64), 256, 0, stream>>>(xh, wqkvh, qkvh, 8192, 3072, 1024);
  vtrans<<<dim3(32, 64), 256, 0, stream>>>(qkvh, vtg);
  attn_fused<<<dim3(16, 64), 256, 0, stream>>>(qkvh, vtg, attnh);
  gemm_bt<0><<<dim3(8, 64), 256, 0, stream>>>(attnh, woh, out, 8192, 1024, 1024);
}